// Round 1
// baseline (1460.652 us; speedup 1.0000x reference)
//
#include <hip/hip_runtime.h>

typedef _Float16 f16;
typedef _Float16 f16x8 __attribute__((ext_vector_type(8)));
typedef float floatx4 __attribute__((ext_vector_type(4)));

__device__ __forceinline__ float ftanh(float x) {
  float ax = __builtin_fabsf(x);
  float e  = __expf(-2.0f * ax);
  float t  = (1.0f - e) * __builtin_amdgcn_rcpf(1.0f + e);
  return x < 0.0f ? -t : t;
}

// async global->LDS, 16B/lane; LDS base wave-uniform, HW scatters lane i to base+i*16.
__device__ __forceinline__ void gll16(const f16* g, f16* l) {
  __builtin_amdgcn_global_load_lds(
      (const __attribute__((address_space(1))) void*)g,
      (__attribute__((address_space(3))) void*)l, 16, 0, 0);
}

// Device-scope grid barrier (fresh counter per wavefront, zeroed by prep_all each
// replay). Release RMW: vmcnt drain (from syncthreads) + buffer_wbl2 -> stores reach
// L3. Relaxed agent spin (no per-poll L2 inv), then one acquire fence (buffer_inv).
__device__ __forceinline__ void gbar(int* cnt, int nb) {
  __syncthreads();
  if (threadIdx.x == 0) {
    __hip_atomic_fetch_add(cnt, 1, __ATOMIC_RELEASE, __HIP_MEMORY_SCOPE_AGENT);
    while (__hip_atomic_load(cnt, __ATOMIC_RELAXED, __HIP_MEMORY_SCOPE_AGENT) < nb)
      __builtin_amdgcn_s_sleep(8);
    __builtin_amdgcn_fence(__ATOMIC_ACQUIRE, "agent");
  }
  __syncthreads();
}

// 128 x (FJ*32) tile GEMM step. A split at k=512 between two sources, W [N][K]
// k-contiguous, bias+tanh epilogue via LDS transpose, out stride 512.
// NEW: T2 XOR-swizzle on the staged tiles (rule #21: linear LDS dest + inverse-
// swizzled GLOBAL source + swizzled ds_read). Row pitch is 128 B, so the old linear
// layout put all 16 lanes of a quad on one 4-bank group (16-way conflict). Each
// gll16 covers one 8-row group (base row % 8 == 0), so row&7 == lane>>3 on the
// store side and lm&7 on the read side.
template<int FJ>
__device__ __forceinline__ void tile_gemm(
    const f16* __restrict__ A0, int ldA0,   // k in [0,512)
    const f16* __restrict__ A1, int ldA1,   // k in [512,K), col index k-512
    int K, const f16* __restrict__ WT,
    const float* __restrict__ bias,
    f16* __restrict__ outp, int bm, int bn, f16* sm)
{
  const int tid  = threadIdx.x;
  const int w    = tid >> 6;
  const int lane = tid & 63;
  const int lm   = lane & 15;
  const int quad = lane >> 4;
  const int wm   = (w >> 1) * 64;
  const int wn   = (w & 1) * (FJ * 16);
  const int srow8 = lane >> 3;
  const int scol  = ((lane & 7) ^ srow8) * 8;   // pre-swizzled global source col
  const int lmx   = lm & 7;

  f16* As0 = sm;
  f16* Ws0 = sm + 128 * 64;

  floatx4 acc[4][FJ];
  #pragma unroll
  for (int i = 0; i < 4; ++i)
    #pragma unroll
    for (int j = 0; j < FJ; ++j)
      acc[i][j] = (floatx4){0.f, 0.f, 0.f, 0.f};

  for (int k0 = 0; k0 < K; k0 += 64) {
    const f16* Asrc = (k0 < 512) ? (A0 + k0) : (A1 + (k0 - 512));
    const int  ld   = (k0 < 512) ? ldA0 : ldA1;
    #pragma unroll
    for (int i = 0; i < 4; ++i) {
      int r = (w * 4 + i) * 8 + srow8;
      gll16(Asrc + (size_t)(bm + r) * ld + scol, As0 + (w * 4 + i) * 512);
    }
    #pragma unroll
    for (int i = 0; i < FJ; ++i) {
      int r = (w * FJ + i) * 8 + srow8;
      gll16(WT + (size_t)(bn + r) * K + k0 + scol, Ws0 + (w * FJ + i) * 512);
    }
    __syncthreads();
    #pragma unroll
    for (int kk = 0; kk < 64; kk += 32) {
      const int sw = (((kk >> 3) + quad) ^ lmx) << 3;  // swizzled 16B-slot, f16 units
      f16x8 a[4], bfr[FJ];
      #pragma unroll
      for (int fi = 0; fi < 4; ++fi)
        a[fi] = *(const f16x8*)&As0[(size_t)(wm + fi * 16 + lm) * 64 + sw];
      #pragma unroll
      for (int fj = 0; fj < FJ; ++fj)
        bfr[fj] = *(const f16x8*)&Ws0[(size_t)(wn + fj * 16 + lm) * 64 + sw];
      #pragma unroll
      for (int fi = 0; fi < 4; ++fi)
        #pragma unroll
        for (int fj = 0; fj < FJ; ++fj)
          acc[fi][fj] = __builtin_amdgcn_mfma_f32_16x16x32_f16(a[fi], bfr[fj], acc[fi][fj], 0, 0, 0);
    }
    __syncthreads();
  }

  // epilogue: C/D layout col=lane&15, row=quad*4+reg [m89/m91] -> LDS transpose
  constexpr int ES = FJ * 32 + 8;
  #pragma unroll
  for (int fi = 0; fi < 4; ++fi)
    #pragma unroll
    for (int fj = 0; fj < FJ; ++fj) {
      int col = wn + fj * 16 + lm;
      #pragma unroll
      for (int r = 0; r < 4; ++r) {
        int row = wm + fi * 16 + quad * 4 + r;
        sm[row * ES + col] = (f16)acc[fi][fj][r];
      }
    }
  __syncthreads();
  constexpr int TPR = (FJ * 32) / 8;     // threads per row
  constexpr int RPP = 256 / TPR;         // rows per pass
  #pragma unroll
  for (int p = 0; p < 128 / RPP; ++p) {
    int row = p * RPP + tid / TPR;
    int c8  = (tid % TPR) * 8;
    f16x8 ve = *(const f16x8*)&sm[row * ES + c8];
    floatx4 bv0 = *(const floatx4*)&bias[bn + c8];
    floatx4 bv1 = *(const floatx4*)&bias[bn + c8 + 4];
    union { f16 e[8]; f16x8 v; } o;
    #pragma unroll
    for (int j = 0; j < 4; ++j) o.e[j]     = (f16)ftanh((float)ve[j]     + bv0[j]);
    #pragma unroll
    for (int j = 0; j < 4; ++j) o.e[4 + j] = (f16)ftanh((float)ve[4 + j] + bv1[j]);
    *(f16x8*)(outp + (size_t)(bm + row) * 512 + bn + c8) = o.v;
  }
}

// Persistent anti-diagonal pipeline: one launch, 22 wavefronts separated by
// device-scope barriers (replaces 22 kernel launches). 512 blocks = exactly
// 2/CU (co-residency guaranteed: launch_bounds(256,2) caps VGPR<=256; LDS
// 34816 B allows 4/CU). Zone roles fixed per block; inactive zones still join
// every barrier. slab<->XCD mapping unchanged: H producer->consumer stays
// intra-XCD, but barriers use full agent scope (same semantics as the old
// kernel boundaries).
__global__ __launch_bounds__(256, 2)
void rnn_persist(const f16* __restrict__ xh,
                 const f16* __restrict__ W0T, const f16* __restrict__ W1T,
                 const f16* __restrict__ W2T,
                 const float* __restrict__ bcomb, const float* __restrict__ b1,
                 const float* __restrict__ b2,
                 f16* __restrict__ H0a, f16* __restrict__ H0b,
                 f16* __restrict__ H1a, f16* __restrict__ H1b,
                 f16* __restrict__ H2a, f16* __restrict__ H2b,
                 int* __restrict__ flags)
{
  __shared__ f16 sm[17408];   // 34816 B: staging 32 KB (FJ=4) / epi 128x136
  const int b   = blockIdx.x;
  const int xcd = b & 7;
  const int r   = b >> 3;     // 0..63

  int zone, slab, bn;
  if (r < 32) { zone = 0; slab = xcd * 4 + (r & 3);  bn = (r >> 2) * 64; }
  else if (r < 48) { int rr = r - 32; zone = 1; slab = xcd * 4 + (rr & 3); bn = (rr >> 2) * 128; }
  else { int rr = r - 48; zone = 2; slab = xcd * 4 + (rr & 3); bn = (rr >> 2) * 128; }

  for (int wv = 0; wv < 22; ++wv) {
    const int cur = wv & 1;
    const f16* H0c = cur ? H0b : H0a;  f16* H0n = cur ? H0a : H0b;
    const f16* H1c = cur ? H1b : H1a;  f16* H1n = cur ? H1a : H1b;
    const f16* H2c = cur ? H2b : H2a;  f16* H2n = cur ? H2a : H2b;

    if (zone == 0) {
      if (wv <= 19)
        tile_gemm<2>(H0c, 512, xh + (size_t)wv * 320, 6400, 832, W0T, bcomb,
                     H0n, slab * 128, bn, sm);
    } else if (zone == 1) {
      if (wv >= 1 && wv <= 20)
        tile_gemm<4>(H0c, 512, H1c, 512, 1024, W1T, b1, H1n, slab * 128, bn, sm);
    } else {
      if (wv >= 2)
        tile_gemm<4>(H1c, 512, H2c, 512, 1024, W2T, b2, H2n, slab * 128, bn, sm);
    }
    if (wv < 21) gbar(&flags[wv], 512);
  }
}

// ---------------------------------------------------------------------------
// Fused prep. NEW xh section: 1600 blocks, 8 chunks/thread with all 8 loads
// issued before any convert/store (256 B in flight/thread) — old version was
// 1 load-pair+1 store per thread, latency-bound at 1.33 TB/s / 7% VALUBusy.
//   [0,1600)         : x fp32 -> xh f16 (zero-padded to 320), 8 chunks/thread
//   [1600,4161)      : Wce = W_emb @ wx0 (split-K x4, LDS reduce) + bcomb
//   [4161,9281)      : weight transposes -> W0T/W1T/W2T
//   [9281,12353)     : zero-init H0a, H1b, H2a
//   [12353]          : zero barrier flags (graph-replay safe)
// ---------------------------------------------------------------------------
#define P_XH  1600
#define P_WCE 4161
#define P_WT  9281
#define P_Z   12353
#define P_FL  12354

__global__ __launch_bounds__(256)
void prep_all(const float* __restrict__ x,
              const float* __restrict__ W_emb, const float* __restrict__ b_emb,
              const float* __restrict__ wx0, const float* __restrict__ wh0,
              const float* __restrict__ b0,
              const float* __restrict__ wx1, const float* __restrict__ wh1,
              const float* __restrict__ wx2, const float* __restrict__ wh2,
              f16* __restrict__ xh, f16* __restrict__ W0T,
              f16* __restrict__ W1T, f16* __restrict__ W2T,
              float* __restrict__ bcomb,
              f16* __restrict__ H0a, f16* __restrict__ H1b, f16* __restrict__ H2a,
              int* __restrict__ flags)
{
  __shared__ float red[256];
  const int b   = blockIdx.x;
  const int tid = threadIdx.x;

  if (b < P_XH) {
    // 1600*256*8 = 3,276,800 chunks of f16x8; stride-coalesced batching
    const int NTH = P_XH * 256;
    const int g = b * 256 + tid;
    floatx4 va[8], vb[8];
    int rw[8], cc[8];
    const floatx4 z4 = {0.f, 0.f, 0.f, 0.f};
    #pragma unroll
    for (int s = 0; s < 8; ++s) {
      int U = g + s * NTH;
      int row = U / 40;
      int c   = (U - row * 40) * 8;
      rw[s] = row; cc[s] = c;
      const float* src = x + (size_t)row * 300 + c;
      va[s] = (c + 4 <= 300) ? *(const floatx4*)src : z4;        // c=296: 4 real
      vb[s] = (c + 8 <= 300) ? *(const floatx4*)(src + 4) : z4;  // c>=296: pad
    }
    #pragma unroll
    for (int s = 0; s < 8; ++s) {
      union { f16 e[8]; f16x8 v; } t;
      #pragma unroll
      for (int j = 0; j < 4; ++j) { t.e[j] = (f16)va[s][j]; t.e[4 + j] = (f16)vb[s][j]; }
      *(f16x8*)(xh + (size_t)rw[s] * 320 + cc[s]) = t.v;
    }
  } else if (b < P_WCE) {
    int bb = b - P_XH;
    if (bb < 2560) {
      // Wce[k][n] = sum_j W_emb[k][j]*wx0[j][n]; 64 outputs x 4 j-chunks per block
      int oidx  = bb * 64 + (tid & 63);     // 0..163839
      int chunk = tid >> 6;                  // 0..3
      int n = oidx & 511, k = oidx >> 9;     // k 0..319
      float s = 0.f;
      if (k < 300) {
        const float* we = W_emb + k * 512 + chunk * 128;
        const float* wx = wx0 + (size_t)(chunk * 128) * 512 + n;
        #pragma unroll 4
        for (int j = 0; j < 128; ++j)
          s = __builtin_fmaf(we[j], wx[(size_t)j * 512], s);
      }
      red[tid] = s;
      __syncthreads();
      if (chunk == 0)
        W0T[(size_t)n * 832 + 512 + k] =
            (f16)(red[tid] + red[tid + 64] + red[tid + 128] + red[tid + 192]);
    } else {
      // bcomb = b0 + b_emb @ wx0 (512 outputs, 2 per thread)
      #pragma unroll
      for (int p = 0; p < 2; ++p) {
        int n = p * 256 + tid;
        float s = b0[n];
        for (int j = 0; j < 512; ++j)
          s = __builtin_fmaf(b_emb[j], wx0[(size_t)j * 512 + n], s);
        bcomb[n] = s;
      }
    }
  } else if (b < P_WT) {
    // transposes: 5120*256 = 1,310,720 elements
    int id = (b - P_WCE) * 256 + tid;
    if (id < 262144) {
      int n = id & 511, k = id >> 9;
      W0T[(size_t)n * 832 + k] = (f16)wh0[k * 512 + n];
    } else if (id < 786432) {
      int i2 = id - 262144;
      int n = i2 & 511, k = i2 >> 9;         // 0..1023
      float v = (k < 512) ? wx1[k * 512 + n] : wh1[(k - 512) * 512 + n];
      W1T[(size_t)n * 1024 + k] = (f16)v;
    } else {
      int i2 = id - 786432;
      int n = i2 & 511, k = i2 >> 9;
      float v = (k < 512) ? wx2[k * 512 + n] : wh2[(k - 512) * 512 + n];
      W2T[(size_t)n * 1024 + k] = (f16)v;
    }
  } else if (b < P_Z) {
    // zero-init h(-1): H0a, H1b, H2a — 3072*256 = 786,432 f16x8 chunks
    int id = (b - P_WT) * 256 + tid;
    f16x8 z8 = {};
    f16* dst = (id < 262144) ? H0a : (id < 524288) ? H1b : H2a;
    *(f16x8*)(dst + (size_t)(id & 262143) * 8) = z8;
  } else {
    if (tid < 32) flags[tid] = 0;
  }
}

// out[4096,10] = h2[4096,512](f16) @ W_fc[512,10] + b_fc; W_fc staged in LDS
__global__ void fc_kernel(const f16* __restrict__ h2,
                          const float* __restrict__ Wfc, const float* __restrict__ bfc,
                          float* __restrict__ out)
{
  __shared__ float wf[5120];
  __shared__ float bf[16];
  const int tid = threadIdx.x;
  for (int i = tid; i < 5120; i += 256) wf[i] = Wfc[i];
  if (tid < 10) bf[tid] = bfc[tid];
  __syncthreads();
  int id = blockIdx.x * 256 + tid;           // 40960 exactly
  int row = id / 10;
  int c = id - row * 10;
  float s = bf[c];
  const f16* hr = h2 + (size_t)row * 512;
  for (int k8 = 0; k8 < 64; ++k8) {
    f16x8 h8 = *(const f16x8*)(hr + k8 * 8);
    #pragma unroll
    for (int j = 0; j < 8; ++j)
      s = __builtin_fmaf((float)h8[j], wf[(k8 * 8 + j) * 10 + c], s);
  }
  out[id] = s;
}

extern "C" void kernel_launch(void* const* d_in, const int* in_sizes, int n_in,
                              void* d_out, int out_size, void* d_ws, size_t ws_size,
                              hipStream_t stream)
{
  (void)in_sizes; (void)n_in; (void)out_size; (void)ws_size;
  const float* x     = (const float*)d_in[0];
  const float* W_emb = (const float*)d_in[1];
  const float* b_emb = (const float*)d_in[2];
  const float* wx0   = (const float*)d_in[3];
  const float* wh0   = (const float*)d_in[4];
  const float* b0    = (const float*)d_in[5];
  const float* wx1   = (const float*)d_in[6];
  const float* wh1   = (const float*)d_in[7];
  const float* b1    = (const float*)d_in[8];
  const float* wx2   = (const float*)d_in[9];
  const float* wh2   = (const float*)d_in[10];
  const float* b2    = (const float*)d_in[11];
  const float* W_fc  = (const float*)d_in[12];
  const float* b_fc  = (const float*)d_in[13];
  float* out = (float*)d_out;

  char* ws = (char*)d_ws;
  size_t off = 0;
  auto alloc = [&](size_t bytes) -> void* {
    void* p = ws + off;
    off = (off + bytes + 255) & ~(size_t)255;
    return p;
  };
  f16*   xh    = (f16*)alloc((size_t)81920 * 320 * 2);   // 52.4 MB
  f16*   W0T   = (f16*)alloc((size_t)512 * 832 * 2);
  f16*   W1T   = (f16*)alloc((size_t)512 * 1024 * 2);
  f16*   W2T   = (f16*)alloc((size_t)512 * 1024 * 2);
  float* bcomb = (float*)alloc(512 * 4);
  f16*   H0a   = (f16*)alloc((size_t)4096 * 512 * 2);
  f16*   H0b   = (f16*)alloc((size_t)4096 * 512 * 2);
  f16*   H1a   = (f16*)alloc((size_t)4096 * 512 * 2);
  f16*   H1b   = (f16*)alloc((size_t)4096 * 512 * 2);
  f16*   H2a   = (f16*)alloc((size_t)4096 * 512 * 2);
  f16*   H2b   = (f16*)alloc((size_t)4096 * 512 * 2);
  int*   flags = (int*)alloc(32 * 4);

  // one fused prep dispatch (xh + Wce + bcomb + transposes + H zero-init + flags)
  prep_all<<<P_FL, 256, 0, stream>>>(x, W_emb, b_emb, wx0, wh0, b0,
                                     wx1, wh1, wx2, wh2,
                                     xh, W0T, W1T, W2T, bcomb, H0a, H1b, H2a,
                                     flags);

  // persistent kernel: 22 anti-diagonal wavefronts, 21 internal device barriers
  rnn_persist<<<512, 256, 0, stream>>>(xh, W0T, W1T, W2T, bcomb, b1, b2,
                                       H0a, H0b, H1a, H1b, H2a, H2b, flags);

  // h2(19) written at wv=21 into H2n(cur=1) = H2a
  fc_kernel<<<160, 256, 0, stream>>>(H2a, W_fc, b_fc, out);
}

// Round 2
// 692.256 us; speedup vs baseline: 2.1100x; 2.1100x over previous
//
#include <hip/hip_runtime.h>

typedef _Float16 f16;
typedef _Float16 f16x8 __attribute__((ext_vector_type(8)));
typedef float floatx4 __attribute__((ext_vector_type(4)));

__device__ __forceinline__ float ftanh(float x) {
  float ax = __builtin_fabsf(x);
  float e  = __expf(-2.0f * ax);
  float t  = (1.0f - e) * __builtin_amdgcn_rcpf(1.0f + e);
  return x < 0.0f ? -t : t;
}

// async global->LDS, 16B/lane; LDS base wave-uniform, HW scatters lane i to base+i*16.
__device__ __forceinline__ void gll16(const f16* g, f16* l) {
  __builtin_amdgcn_global_load_lds(
      (const __attribute__((address_space(1))) void*)g,
      (__attribute__((address_space(3))) void*)l, 16, 0, 0);
}

// 128 x (FJ*32) tile GEMM step. A split at k=512 between two sources, W [N][K]
// k-contiguous, bias+tanh epilogue via LDS transpose, out stride 512.
// T2 XOR-swizzle on the staged tiles (rule #21: linear LDS dest + inverse-swizzled
// GLOBAL source + swizzled ds_read). Row pitch is 128 B, so a linear layout puts all
// 16 lanes of a quad on one 4-bank group (16-way conflict). Each gll16 covers one
// 8-row group, so row&7 == lane>>3 on the store side and lm&7 on the read side.
// Verified round 1: SQ_LDS_BANK_CONFLICT ~45K/wavefront (~3% of ds_reads), passed.
template<int FJ>
__device__ __forceinline__ void tile_gemm(
    const f16* __restrict__ A0, int ldA0,   // k in [0,512)
    const f16* __restrict__ A1, int ldA1,   // k in [512,K), col index k-512
    int K, const f16* __restrict__ WT,
    const float* __restrict__ bias,
    f16* __restrict__ outp, int bm, int bn, f16* sm)
{
  const int tid  = threadIdx.x;
  const int w    = tid >> 6;
  const int lane = tid & 63;
  const int lm   = lane & 15;
  const int quad = lane >> 4;
  const int wm   = (w >> 1) * 64;
  const int wn   = (w & 1) * (FJ * 16);
  const int srow8 = lane >> 3;
  const int scol  = ((lane & 7) ^ srow8) * 8;   // pre-swizzled global source col
  const int lmx   = lm & 7;

  f16* As0 = sm;
  f16* Ws0 = sm + 128 * 64;

  floatx4 acc[4][FJ];
  #pragma unroll
  for (int i = 0; i < 4; ++i)
    #pragma unroll
    for (int j = 0; j < FJ; ++j)
      acc[i][j] = (floatx4){0.f, 0.f, 0.f, 0.f};

  for (int k0 = 0; k0 < K; k0 += 64) {
    const f16* Asrc = (k0 < 512) ? (A0 + k0) : (A1 + (k0 - 512));
    const int  ld   = (k0 < 512) ? ldA0 : ldA1;
    #pragma unroll
    for (int i = 0; i < 4; ++i) {
      int r = (w * 4 + i) * 8 + srow8;
      gll16(Asrc + (size_t)(bm + r) * ld + scol, As0 + (w * 4 + i) * 512);
    }
    #pragma unroll
    for (int i = 0; i < FJ; ++i) {
      int r = (w * FJ + i) * 8 + srow8;
      gll16(WT + (size_t)(bn + r) * K + k0 + scol, Ws0 + (w * FJ + i) * 512);
    }
    __syncthreads();
    #pragma unroll
    for (int kk = 0; kk < 64; kk += 32) {
      const int sw = (((kk >> 3) + quad) ^ lmx) << 3;  // swizzled 16B-slot, f16 units
      f16x8 a[4], bfr[FJ];
      #pragma unroll
      for (int fi = 0; fi < 4; ++fi)
        a[fi] = *(const f16x8*)&As0[(size_t)(wm + fi * 16 + lm) * 64 + sw];
      #pragma unroll
      for (int fj = 0; fj < FJ; ++fj)
        bfr[fj] = *(const f16x8*)&Ws0[(size_t)(wn + fj * 16 + lm) * 64 + sw];
      #pragma unroll
      for (int fi = 0; fi < 4; ++fi)
        #pragma unroll
        for (int fj = 0; fj < FJ; ++fj)
          acc[fi][fj] = __builtin_amdgcn_mfma_f32_16x16x32_f16(a[fi], bfr[fj], acc[fi][fj], 0, 0, 0);
    }
    __syncthreads();
  }

  // epilogue: C/D layout col=lane&15, row=quad*4+reg [m89/m91] -> LDS transpose
  constexpr int ES = FJ * 32 + 8;
  #pragma unroll
  for (int fi = 0; fi < 4; ++fi)
    #pragma unroll
    for (int fj = 0; fj < FJ; ++fj) {
      int col = wn + fj * 16 + lm;
      #pragma unroll
      for (int r = 0; r < 4; ++r) {
        int row = wm + fi * 16 + quad * 4 + r;
        sm[row * ES + col] = (f16)acc[fi][fj][r];
      }
    }
  __syncthreads();
  constexpr int TPR = (FJ * 32) / 8;     // threads per row
  constexpr int RPP = 256 / TPR;         // rows per pass
  #pragma unroll
  for (int p = 0; p < 128 / RPP; ++p) {
    int row = p * RPP + tid / TPR;
    int c8  = (tid % TPR) * 8;
    f16x8 ve = *(const f16x8*)&sm[row * ES + c8];
    floatx4 bv0 = *(const floatx4*)&bias[bn + c8];
    floatx4 bv1 = *(const floatx4*)&bias[bn + c8 + 4];
    union { f16 e[8]; f16x8 v; } o;
    #pragma unroll
    for (int j = 0; j < 4; ++j) o.e[j]     = (f16)ftanh((float)ve[j]     + bv0[j]);
    #pragma unroll
    for (int j = 0; j < 4; ++j) o.e[4 + j] = (f16)ftanh((float)ve[4 + j] + bv1[j]);
    *(f16x8*)(outp + (size_t)(bm + row) * 512 + bn + c8) = o.v;
  }
}

// One anti-diagonal wavefront: 512 blocks, 2/CU, balanced. slab<->XCD fixed
// across layers/wavefronts so H tiles stay in the home XCD's L2/L3.
// Round-1 lesson: do NOT replace these launches with a persistent kernel +
// software grid barrier — 512 spinners on one flag line + per-block
// wbl2/inv fences cost ~25 us/barrier more than the HW dispatch path.
__global__ __launch_bounds__(256, 2)
void rnn_step(int wv, const f16* __restrict__ xh,
              const f16* __restrict__ W0T, const f16* __restrict__ W1T,
              const f16* __restrict__ W2T,
              const float* __restrict__ bcomb, const float* __restrict__ b1,
              const float* __restrict__ b2,
              const f16* __restrict__ H0c, f16* __restrict__ H0n,
              const f16* __restrict__ H1c, f16* __restrict__ H1n,
              const f16* __restrict__ H2c, f16* __restrict__ H2n)
{
  __shared__ f16 sm[17408];   // 34816 B: staging 32 KB (FJ=4) / epi 128x136
  const int b   = blockIdx.x;
  const int xcd = b & 7;
  const int r   = b >> 3;     // 0..63

  if (r < 32) {               // z0: 256 blocks, tile 128x64, K=832
    if (wv > 19) return;
    const int slab = xcd * 4 + (r & 3);
    const int bn   = (r >> 2) * 64;
    tile_gemm<2>(H0c, 512, xh + (size_t)wv * 320, 6400, 832, W0T, bcomb,
                 H0n, slab * 128, bn, sm);
  } else if (r < 48) {        // z1: 128 blocks, tile 128x128, K=1024
    if (wv < 1 || wv > 20) return;
    const int rr   = r - 32;
    const int slab = xcd * 4 + (rr & 3);
    const int bn   = (rr >> 2) * 128;
    tile_gemm<4>(H0c, 512, H1c, 512, 1024, W1T, b1, H1n, slab * 128, bn, sm);
  } else {                    // z2: 128 blocks, tile 128x128, K=1024
    if (wv < 2) return;
    const int rr   = r - 48;
    const int slab = xcd * 4 + (rr & 3);
    const int bn   = (rr >> 2) * 128;
    tile_gemm<4>(H1c, 512, H2c, 512, 1024, W2T, b2, H2n, slab * 128, bn, sm);
  }
}

// ---------------------------------------------------------------------------
// Fused prep. xh section: 1600 blocks, 8 chunks/thread with all 8 loads issued
// before any convert/store (256 B in flight/thread) — the 1-chunk/thread
// version was latency-bound at 1.33 TB/s / 7% VALUBusy / 99 us.
//   [0,1600)         : x fp32 -> xh f16 (zero-padded to 320), 8 chunks/thread
//   [1600,4161)      : Wce = W_emb @ wx0 (split-K x4, LDS reduce) + bcomb
//   [4161,9281)      : weight transposes -> W0T/W1T/W2T
//   [9281,12353)     : zero-init H0a, H1b, H2a
// ---------------------------------------------------------------------------
#define P_XH  1600
#define P_WCE 4161
#define P_WT  9281
#define P_Z   12353

__global__ __launch_bounds__(256)
void prep_all(const float* __restrict__ x,
              const float* __restrict__ W_emb, const float* __restrict__ b_emb,
              const float* __restrict__ wx0, const float* __restrict__ wh0,
              const float* __restrict__ b0,
              const float* __restrict__ wx1, const float* __restrict__ wh1,
              const float* __restrict__ wx2, const float* __restrict__ wh2,
              f16* __restrict__ xh, f16* __restrict__ W0T,
              f16* __restrict__ W1T, f16* __restrict__ W2T,
              float* __restrict__ bcomb,
              f16* __restrict__ H0a, f16* __restrict__ H1b, f16* __restrict__ H2a)
{
  __shared__ float red[256];
  const int b   = blockIdx.x;
  const int tid = threadIdx.x;

  if (b < P_XH) {
    // 1600*256*8 = 3,276,800 chunks of f16x8; stride-coalesced batching
    const int NTH = P_XH * 256;
    const int g = b * 256 + tid;
    floatx4 va[8], vb[8];
    int rw[8], cc[8];
    const floatx4 z4 = {0.f, 0.f, 0.f, 0.f};
    #pragma unroll
    for (int s = 0; s < 8; ++s) {
      int U = g + s * NTH;
      int row = U / 40;
      int c   = (U - row * 40) * 8;
      rw[s] = row; cc[s] = c;
      const float* src = x + (size_t)row * 300 + c;
      va[s] = (c + 4 <= 300) ? *(const floatx4*)src : z4;        // c=296: 4 real
      vb[s] = (c + 8 <= 300) ? *(const floatx4*)(src + 4) : z4;  // c>=296: pad
    }
    #pragma unroll
    for (int s = 0; s < 8; ++s) {
      union { f16 e[8]; f16x8 v; } t;
      #pragma unroll
      for (int j = 0; j < 4; ++j) { t.e[j] = (f16)va[s][j]; t.e[4 + j] = (f16)vb[s][j]; }
      *(f16x8*)(xh + (size_t)rw[s] * 320 + cc[s]) = t.v;
    }
  } else if (b < P_WCE) {
    int bb = b - P_XH;
    if (bb < 2560) {
      // Wce[k][n] = sum_j W_emb[k][j]*wx0[j][n]; 64 outputs x 4 j-chunks per block
      int oidx  = bb * 64 + (tid & 63);     // 0..163839
      int chunk = tid >> 6;                  // 0..3
      int n = oidx & 511, k = oidx >> 9;     // k 0..319
      float s = 0.f;
      if (k < 300) {
        const float* we = W_emb + k * 512 + chunk * 128;
        const float* wx = wx0 + (size_t)(chunk * 128) * 512 + n;
        #pragma unroll 4
        for (int j = 0; j < 128; ++j)
          s = __builtin_fmaf(we[j], wx[(size_t)j * 512], s);
      }
      red[tid] = s;
      __syncthreads();
      if (chunk == 0)
        W0T[(size_t)n * 832 + 512 + k] =
            (f16)(red[tid] + red[tid + 64] + red[tid + 128] + red[tid + 192]);
    } else {
      // bcomb = b0 + b_emb @ wx0 (512 outputs, 2 per thread)
      #pragma unroll
      for (int p = 0; p < 2; ++p) {
        int n = p * 256 + tid;
        float s = b0[n];
        for (int j = 0; j < 512; ++j)
          s = __builtin_fmaf(b_emb[j], wx0[(size_t)j * 512 + n], s);
        bcomb[n] = s;
      }
    }
  } else if (b < P_WT) {
    // transposes: 5120*256 = 1,310,720 elements
    int id = (b - P_WCE) * 256 + tid;
    if (id < 262144) {
      int n = id & 511, k = id >> 9;
      W0T[(size_t)n * 832 + k] = (f16)wh0[k * 512 + n];
    } else if (id < 786432) {
      int i2 = id - 262144;
      int n = i2 & 511, k = i2 >> 9;         // 0..1023
      float v = (k < 512) ? wx1[k * 512 + n] : wh1[(k - 512) * 512 + n];
      W1T[(size_t)n * 1024 + k] = (f16)v;
    } else {
      int i2 = id - 786432;
      int n = i2 & 511, k = i2 >> 9;
      float v = (k < 512) ? wx2[k * 512 + n] : wh2[(k - 512) * 512 + n];
      W2T[(size_t)n * 1024 + k] = (f16)v;
    }
  } else {
    // zero-init h(-1): H0a, H1b, H2a — 3072*256 = 786,432 f16x8 chunks
    int id = (b - P_WT) * 256 + tid;
    f16x8 z8 = {};
    f16* dst = (id < 262144) ? H0a : (id < 524288) ? H1b : H2a;
    *(f16x8*)(dst + (size_t)(id & 262143) * 8) = z8;
  }
}

// out[4096,10] = h2[4096,512](f16) @ W_fc[512,10] + b_fc; W_fc staged in LDS
__global__ void fc_kernel(const f16* __restrict__ h2,
                          const float* __restrict__ Wfc, const float* __restrict__ bfc,
                          float* __restrict__ out)
{
  __shared__ float wf[5120];
  __shared__ float bf[16];
  const int tid = threadIdx.x;
  for (int i = tid; i < 5120; i += 256) wf[i] = Wfc[i];
  if (tid < 10) bf[tid] = bfc[tid];
  __syncthreads();
  int id = blockIdx.x * 256 + tid;           // 40960 exactly
  int row = id / 10;
  int c = id - row * 10;
  float s = bf[c];
  const f16* hr = h2 + (size_t)row * 512;
  for (int k8 = 0; k8 < 64; ++k8) {
    f16x8 h8 = *(const f16x8*)(hr + k8 * 8);
    #pragma unroll
    for (int j = 0; j < 8; ++j)
      s = __builtin_fmaf((float)h8[j], wf[(k8 * 8 + j) * 10 + c], s);
  }
  out[id] = s;
}

extern "C" void kernel_launch(void* const* d_in, const int* in_sizes, int n_in,
                              void* d_out, int out_size, void* d_ws, size_t ws_size,
                              hipStream_t stream)
{
  (void)in_sizes; (void)n_in; (void)out_size; (void)ws_size;
  const float* x     = (const float*)d_in[0];
  const float* W_emb = (const float*)d_in[1];
  const float* b_emb = (const float*)d_in[2];
  const float* wx0   = (const float*)d_in[3];
  const float* wh0   = (const float*)d_in[4];
  const float* b0    = (const float*)d_in[5];
  const float* wx1   = (const float*)d_in[6];
  const float* wh1   = (const float*)d_in[7];
  const float* b1    = (const float*)d_in[8];
  const float* wx2   = (const float*)d_in[9];
  const float* wh2   = (const float*)d_in[10];
  const float* b2    = (const float*)d_in[11];
  const float* W_fc  = (const float*)d_in[12];
  const float* b_fc  = (const float*)d_in[13];
  float* out = (float*)d_out;

  char* ws = (char*)d_ws;
  size_t off = 0;
  auto alloc = [&](size_t bytes) -> void* {
    void* p = ws + off;
    off = (off + bytes + 255) & ~(size_t)255;
    return p;
  };
  f16*   xh    = (f16*)alloc((size_t)81920 * 320 * 2);   // 52.4 MB
  f16*   W0T   = (f16*)alloc((size_t)512 * 832 * 2);
  f16*   W1T   = (f16*)alloc((size_t)512 * 1024 * 2);
  f16*   W2T   = (f16*)alloc((size_t)512 * 1024 * 2);
  float* bcomb = (float*)alloc(512 * 4);
  f16*   H0a   = (f16*)alloc((size_t)4096 * 512 * 2);
  f16*   H0b   = (f16*)alloc((size_t)4096 * 512 * 2);
  f16*   H1a   = (f16*)alloc((size_t)4096 * 512 * 2);
  f16*   H1b   = (f16*)alloc((size_t)4096 * 512 * 2);
  f16*   H2a   = (f16*)alloc((size_t)4096 * 512 * 2);
  f16*   H2b   = (f16*)alloc((size_t)4096 * 512 * 2);

  // one fused prep dispatch (xh + Wce + bcomb + transposes + H zero-init)
  prep_all<<<P_Z, 256, 0, stream>>>(x, W_emb, b_emb, wx0, wh0, b0,
                                    wx1, wh1, wx2, wh2,
                                    xh, W0T, W1T, W2T, bcomb, H0a, H1b, H2a);

  // 22 anti-diagonal wavefronts: z0(t=wv), z1(t=wv-1), z2(t=wv-2)
  for (int wv = 0; wv < 22; ++wv) {
    const int cur = wv & 1;
    f16* H0c = cur ? H0b : H0a;  f16* H0n = cur ? H0a : H0b;
    f16* H1c = cur ? H1b : H1a;  f16* H1n = cur ? H1a : H1b;
    f16* H2c = cur ? H2b : H2a;  f16* H2n = cur ? H2a : H2b;
    rnn_step<<<512, 256, 0, stream>>>(wv, xh, W0T, W1T, W2T, bcomb, b1, b2,
                                      H0c, H0n, H1c, H1n, H2c, H2n);
  }

  // h2(19) written at wv=21 into H2n(cur=1) = H2a
  fc_kernel<<<160, 256, 0, stream>>>(H2a, W_fc, b_fc, out);
}

// Round 3
// 592.074 us; speedup vs baseline: 2.4670x; 1.1692x over previous
//
#include <hip/hip_runtime.h>

typedef _Float16 f16;
typedef _Float16 f16x8 __attribute__((ext_vector_type(8)));
typedef float floatx4 __attribute__((ext_vector_type(4)));

__device__ __forceinline__ float ftanh(float x) {
  float ax = __builtin_fabsf(x);
  float e  = __expf(-2.0f * ax);
  float t  = (1.0f - e) * __builtin_amdgcn_rcpf(1.0f + e);
  return x < 0.0f ? -t : t;
}

// async global->LDS, 16B/lane; LDS base wave-uniform, HW scatters lane i to base+i*16.
__device__ __forceinline__ void gll16(const f16* g, f16* l) {
  __builtin_amdgcn_global_load_lds(
      (const __attribute__((address_space(1))) void*)g,
      (__attribute__((address_space(3))) void*)l, 16, 0, 0);
}

// 128 x (FJ*32) tile GEMM step. A split at k=512 between two sources, W [N][K]
// k-contiguous, bias+tanh epilogue via LDS transpose, out stride 512.
// T2 XOR-swizzle on staged tiles (verified round 1/2: conflicts ~3%, +17% rnn).
// ROUND 3: double-buffered staging, ONE barrier per K-step. stage(t+1) is issued
// BEFORE compute(t), so L2 latency (~300-500cy) hides under ds_read+MFMA. The
// __syncthreads at step end drains vmcnt (stage t+1) and releases the buffer the
// step just read (overwritten only at step t+1's stage of t+2). At 2 blocks/CU
// and 13-16 K-steps the old 2-barrier form exposed full stage latency per step.
template<int FJ>
__device__ __forceinline__ void tile_gemm(
    const f16* __restrict__ A0, int ldA0,   // k in [0,512)
    const f16* __restrict__ A1, int ldA1,   // k in [512,K), col index k-512
    int K, const f16* __restrict__ WT,
    const float* __restrict__ bias,
    f16* __restrict__ outp, int bm, int bn, f16* sm)
{
  const int tid  = threadIdx.x;
  const int w    = tid >> 6;
  const int lane = tid & 63;
  const int lm   = lane & 15;
  const int quad = lane >> 4;
  const int wm   = (w >> 1) * 64;
  const int wn   = (w & 1) * (FJ * 16);
  const int srow8 = lane >> 3;
  const int scol  = ((lane & 7) ^ srow8) * 8;   // pre-swizzled global source col
  const int lmx   = lane & 7;
  constexpr int SB = 8192 + FJ * 2048;          // f16 units per LDS buffer (A+B)

  floatx4 acc[4][FJ];
  #pragma unroll
  for (int i = 0; i < 4; ++i)
    #pragma unroll
    for (int j = 0; j < FJ; ++j)
      acc[i][j] = (floatx4){0.f, 0.f, 0.f, 0.f};

  auto stage = [&](int buf, int k0) {
    const f16* Asrc = (k0 < 512) ? (A0 + k0) : (A1 + (k0 - 512));
    const int  ld   = (k0 < 512) ? ldA0 : ldA1;
    f16* As0 = sm + buf * SB;
    f16* Ws0 = As0 + 8192;
    #pragma unroll
    for (int i = 0; i < 4; ++i) {
      int r = (w * 4 + i) * 8 + srow8;
      gll16(Asrc + (size_t)(bm + r) * ld + scol, As0 + (w * 4 + i) * 512);
    }
    #pragma unroll
    for (int i = 0; i < FJ; ++i) {
      int r = (w * FJ + i) * 8 + srow8;
      gll16(WT + (size_t)(bn + r) * K + k0 + scol, Ws0 + (w * FJ + i) * 512);
    }
  };

  const int NS = K >> 6;
  stage(0, 0);
  __syncthreads();                      // drains stage(0): implicit vmcnt(0)
  for (int s = 0; s < NS; ++s) {
    if (s + 1 < NS) stage((s + 1) & 1, (s + 1) << 6);   // prefetch next tile
    const f16* As0 = sm + (s & 1) * SB;
    const f16* Ws0 = As0 + 8192;
    #pragma unroll
    for (int kk = 0; kk < 64; kk += 32) {
      const int sw = (((kk >> 3) + quad) ^ lmx) << 3;  // swizzled 16B-slot, f16 units
      f16x8 a[4], bfr[FJ];
      #pragma unroll
      for (int fi = 0; fi < 4; ++fi)
        a[fi] = *(const f16x8*)&As0[(size_t)(wm + fi * 16 + lm) * 64 + sw];
      #pragma unroll
      for (int fj = 0; fj < FJ; ++fj)
        bfr[fj] = *(const f16x8*)&Ws0[(size_t)(wn + fj * 16 + lm) * 64 + sw];
      #pragma unroll
      for (int fi = 0; fi < 4; ++fi)
        #pragma unroll
        for (int fj = 0; fj < FJ; ++fj)
          acc[fi][fj] = __builtin_amdgcn_mfma_f32_16x16x32_f16(a[fi], bfr[fj], acc[fi][fj], 0, 0, 0);
    }
    __syncthreads();   // waits stage(s+1) (vmcnt0) + releases buf(s&1) for reuse
  }

  // epilogue: C/D layout col=lane&15, row=quad*4+reg [m89/m91] -> LDS transpose
  constexpr int ES = FJ * 32 + 8;
  #pragma unroll
  for (int fi = 0; fi < 4; ++fi)
    #pragma unroll
    for (int fj = 0; fj < FJ; ++fj) {
      int col = wn + fj * 16 + lm;
      #pragma unroll
      for (int r = 0; r < 4; ++r) {
        int row = wm + fi * 16 + quad * 4 + r;
        sm[row * ES + col] = (f16)acc[fi][fj][r];
      }
    }
  __syncthreads();
  constexpr int TPR = (FJ * 32) / 8;     // threads per row
  constexpr int RPP = 256 / TPR;         // rows per pass
  #pragma unroll
  for (int p = 0; p < 128 / RPP; ++p) {
    int row = p * RPP + tid / TPR;
    int c8  = (tid % TPR) * 8;
    f16x8 ve = *(const f16x8*)&sm[row * ES + c8];
    floatx4 bv0 = *(const floatx4*)&bias[bn + c8];
    floatx4 bv1 = *(const floatx4*)&bias[bn + c8 + 4];
    union { f16 e[8]; f16x8 v; } o;
    #pragma unroll
    for (int j = 0; j < 4; ++j) o.e[j]     = (f16)ftanh((float)ve[j]     + bv0[j]);
    #pragma unroll
    for (int j = 0; j < 4; ++j) o.e[4 + j] = (f16)ftanh((float)ve[4 + j] + bv1[j]);
    *(f16x8*)(outp + (size_t)(bm + row) * 512 + bn + c8) = o.v;
  }
}

// One anti-diagonal wavefront: 512 blocks, 2/CU, balanced (each CU pairs one z0
// with one z1/z2 block). slab<->XCD fixed across layers/wavefronts so H tiles
// stay in the home XCD's L2. Round-1 lesson: do NOT replace these launches with
// a persistent kernel + software grid barrier (~25 us/barrier worse).
__global__ __launch_bounds__(256, 2)
void rnn_step(int wv, const f16* __restrict__ xh,
              const f16* __restrict__ W0T, const f16* __restrict__ W1T,
              const f16* __restrict__ W2T,
              const float* __restrict__ bcomb, const float* __restrict__ b1,
              const float* __restrict__ b2,
              const f16* __restrict__ H0c, f16* __restrict__ H0n,
              const f16* __restrict__ H1c, f16* __restrict__ H1n,
              const f16* __restrict__ H2c, f16* __restrict__ H2n)
{
  __shared__ f16 sm[32768];   // 64 KB: dbuf staging 2x32KB (FJ=4) / epi 128x136
  const int b   = blockIdx.x;
  const int xcd = b & 7;
  const int r   = b >> 3;     // 0..63

  if (r < 32) {               // z0: 256 blocks, tile 128x64, K=832
    if (wv > 19) return;
    const int slab = xcd * 4 + (r & 3);
    const int bn   = (r >> 2) * 64;
    tile_gemm<2>(H0c, 512, xh + (size_t)wv * 320, 6400, 832, W0T, bcomb,
                 H0n, slab * 128, bn, sm);
  } else if (r < 48) {        // z1: 128 blocks, tile 128x128, K=1024
    if (wv < 1 || wv > 20) return;
    const int rr   = r - 32;
    const int slab = xcd * 4 + (rr & 3);
    const int bn   = (rr >> 2) * 128;
    tile_gemm<4>(H0c, 512, H1c, 512, 1024, W1T, b1, H1n, slab * 128, bn, sm);
  } else {                    // z2: 128 blocks, tile 128x128, K=1024
    if (wv < 2) return;
    const int rr   = r - 48;
    const int slab = xcd * 4 + (rr & 3);
    const int bn   = (rr >> 2) * 128;
    tile_gemm<4>(H1c, 512, H2c, 512, 1024, W2T, b2, H2n, slab * 128, bn, sm);
  }
}

// ---------------------------------------------------------------------------
// Fused prep.
//   [0,1600)         : x fp32 -> xh f16 (zero-padded to 320), 8 chunks/thread
//   [1600,4161)      : Wce = W_emb @ wx0 (split-K x4, LDS reduce) + bcomb
//   [4161,4801)      : weight transposes -> W0T/W1T/W2T, f16x8 stores
//                      (round-3: was 2-byte scattered stores, 64 lines/wave RMW)
//   [4801,7873)      : zero-init H0a, H1b, H2a
// ---------------------------------------------------------------------------
#define P_XH  1600
#define P_WCE 4161
#define P_WT  4801
#define P_Z   7873

__global__ __launch_bounds__(256)
void prep_all(const float* __restrict__ x,
              const float* __restrict__ W_emb, const float* __restrict__ b_emb,
              const float* __restrict__ wx0, const float* __restrict__ wh0,
              const float* __restrict__ b0,
              const float* __restrict__ wx1, const float* __restrict__ wh1,
              const float* __restrict__ wx2, const float* __restrict__ wh2,
              f16* __restrict__ xh, f16* __restrict__ W0T,
              f16* __restrict__ W1T, f16* __restrict__ W2T,
              float* __restrict__ bcomb,
              f16* __restrict__ H0a, f16* __restrict__ H1b, f16* __restrict__ H2a)
{
  __shared__ float red[256];
  const int b   = blockIdx.x;
  const int tid = threadIdx.x;

  if (b < P_XH) {
    // 1600*256*8 = 3,276,800 chunks of f16x8; stride-coalesced batching
    const int NTH = P_XH * 256;
    const int g = b * 256 + tid;
    floatx4 va[8], vb[8];
    int rw[8], cc[8];
    const floatx4 z4 = {0.f, 0.f, 0.f, 0.f};
    #pragma unroll
    for (int s = 0; s < 8; ++s) {
      int U = g + s * NTH;
      int row = U / 40;
      int c   = (U - row * 40) * 8;
      rw[s] = row; cc[s] = c;
      const float* src = x + (size_t)row * 300 + c;
      va[s] = (c + 4 <= 300) ? *(const floatx4*)src : z4;        // c=296: 4 real
      vb[s] = (c + 8 <= 300) ? *(const floatx4*)(src + 4) : z4;  // c>=296: pad
    }
    #pragma unroll
    for (int s = 0; s < 8; ++s) {
      union { f16 e[8]; f16x8 v; } t;
      #pragma unroll
      for (int j = 0; j < 4; ++j) { t.e[j] = (f16)va[s][j]; t.e[4 + j] = (f16)vb[s][j]; }
      *(f16x8*)(xh + (size_t)rw[s] * 320 + cc[s]) = t.v;
    }
  } else if (b < P_WCE) {
    int bb = b - P_XH;
    if (bb < 2560) {
      // Wce[k][n] = sum_j W_emb[k][j]*wx0[j][n]; 64 outputs x 4 j-chunks per block
      int oidx  = bb * 64 + (tid & 63);     // 0..163839
      int chunk = tid >> 6;                  // 0..3
      int n = oidx & 511, k = oidx >> 9;     // k 0..319
      float s = 0.f;
      if (k < 300) {
        const float* we = W_emb + k * 512 + chunk * 128;
        const float* wx = wx0 + (size_t)(chunk * 128) * 512 + n;
        #pragma unroll 4
        for (int j = 0; j < 128; ++j)
          s = __builtin_fmaf(we[j], wx[(size_t)j * 512], s);
      }
      red[tid] = s;
      __syncthreads();
      if (chunk == 0)
        W0T[(size_t)n * 832 + 512 + k] =
            (f16)(red[tid] + red[tid + 64] + red[tid + 128] + red[tid + 192]);
    } else {
      // bcomb = b0 + b_emb @ wx0 (512 outputs, 2 per thread)
      #pragma unroll
      for (int p = 0; p < 2; ++p) {
        int n = p * 256 + tid;
        float s = b0[n];
        for (int j = 0; j < 512; ++j)
          s = __builtin_fmaf(b_emb[j], wx0[(size_t)j * 512 + n], s);
        bcomb[n] = s;
      }
    }
  } else if (b < P_WT) {
    // transposes, f16x8 stores: 640*256 = 163,840 k8-chunks
    int id = (b - P_WCE) * 256 + tid;
    if (id < 32768) {                        // W0T k<512 from wh0
      int n = id & 511, k8 = id >> 9;        // k8 0..63
      union { f16 e[8]; f16x8 v; } t;
      #pragma unroll
      for (int j = 0; j < 8; ++j) t.e[j] = (f16)wh0[(size_t)(k8 * 8 + j) * 512 + n];
      *(f16x8*)&W0T[(size_t)n * 832 + k8 * 8] = t.v;
    } else if (id < 98304) {                 // W1T from wx1/wh1
      int i2 = id - 32768;
      int n = i2 & 511, k8 = i2 >> 9;        // k8 0..127; chunks don't straddle 512
      union { f16 e[8]; f16x8 v; } t;
      const float* src = (k8 < 64) ? (wx1 + (size_t)(k8 * 8) * 512 + n)
                                   : (wh1 + (size_t)((k8 - 64) * 8) * 512 + n);
      #pragma unroll
      for (int j = 0; j < 8; ++j) t.e[j] = (f16)src[(size_t)j * 512];
      *(f16x8*)&W1T[(size_t)n * 1024 + k8 * 8] = t.v;
    } else {                                 // W2T from wx2/wh2
      int i2 = id - 98304;
      int n = i2 & 511, k8 = i2 >> 9;
      union { f16 e[8]; f16x8 v; } t;
      const float* src = (k8 < 64) ? (wx2 + (size_t)(k8 * 8) * 512 + n)
                                   : (wh2 + (size_t)((k8 - 64) * 8) * 512 + n);
      #pragma unroll
      for (int j = 0; j < 8; ++j) t.e[j] = (f16)src[(size_t)j * 512];
      *(f16x8*)&W2T[(size_t)n * 1024 + k8 * 8] = t.v;
    }
  } else {
    // zero-init h(-1): H0a, H1b, H2a — 3072*256 = 786,432 f16x8 chunks
    int id = (b - P_WT) * 256 + tid;
    f16x8 z8 = {};
    f16* dst = (id < 262144) ? H0a : (id < 524288) ? H1b : H2a;
    *(f16x8*)(dst + (size_t)(id & 262143) * 8) = z8;
  }
}

// out[4096,10] = h2[4096,512](f16) @ W_fc[512,10] + b_fc; W_fc staged in LDS
__global__ void fc_kernel(const f16* __restrict__ h2,
                          const float* __restrict__ Wfc, const float* __restrict__ bfc,
                          float* __restrict__ out)
{
  __shared__ float wf[5120];
  __shared__ float bf[16];
  const int tid = threadIdx.x;
  for (int i = tid; i < 5120; i += 256) wf[i] = Wfc[i];
  if (tid < 10) bf[tid] = bfc[tid];
  __syncthreads();
  int id = blockIdx.x * 256 + tid;           // 40960 exactly
  int row = id / 10;
  int c = id - row * 10;
  float s = bf[c];
  const f16* hr = h2 + (size_t)row * 512;
  for (int k8 = 0; k8 < 64; ++k8) {
    f16x8 h8 = *(const f16x8*)(hr + k8 * 8);
    #pragma unroll
    for (int j = 0; j < 8; ++j)
      s = __builtin_fmaf((float)h8[j], wf[(k8 * 8 + j) * 10 + c], s);
  }
  out[id] = s;
}

extern "C" void kernel_launch(void* const* d_in, const int* in_sizes, int n_in,
                              void* d_out, int out_size, void* d_ws, size_t ws_size,
                              hipStream_t stream)
{
  (void)in_sizes; (void)n_in; (void)out_size; (void)ws_size;
  const float* x     = (const float*)d_in[0];
  const float* W_emb = (const float*)d_in[1];
  const float* b_emb = (const float*)d_in[2];
  const float* wx0   = (const float*)d_in[3];
  const float* wh0   = (const float*)d_in[4];
  const float* b0    = (const float*)d_in[5];
  const float* wx1   = (const float*)d_in[6];
  const float* wh1   = (const float*)d_in[7];
  const float* b1    = (const float*)d_in[8];
  const float* wx2   = (const float*)d_in[9];
  const float* wh2   = (const float*)d_in[10];
  const float* b2    = (const float*)d_in[11];
  const float* W_fc  = (const float*)d_in[12];
  const float* b_fc  = (const float*)d_in[13];
  float* out = (float*)d_out;

  char* ws = (char*)d_ws;
  size_t off = 0;
  auto alloc = [&](size_t bytes) -> void* {
    void* p = ws + off;
    off = (off + bytes + 255) & ~(size_t)255;
    return p;
  };
  f16*   xh    = (f16*)alloc((size_t)81920 * 320 * 2);   // 52.4 MB
  f16*   W0T   = (f16*)alloc((size_t)512 * 832 * 2);
  f16*   W1T   = (f16*)alloc((size_t)512 * 1024 * 2);
  f16*   W2T   = (f16*)alloc((size_t)512 * 1024 * 2);
  float* bcomb = (float*)alloc(512 * 4);
  f16*   H0a   = (f16*)alloc((size_t)4096 * 512 * 2);
  f16*   H0b   = (f16*)alloc((size_t)4096 * 512 * 2);
  f16*   H1a   = (f16*)alloc((size_t)4096 * 512 * 2);
  f16*   H1b   = (f16*)alloc((size_t)4096 * 512 * 2);
  f16*   H2a   = (f16*)alloc((size_t)4096 * 512 * 2);
  f16*   H2b   = (f16*)alloc((size_t)4096 * 512 * 2);

  // one fused prep dispatch (xh + Wce + bcomb + transposes + H zero-init)
  prep_all<<<P_Z, 256, 0, stream>>>(x, W_emb, b_emb, wx0, wh0, b0,
                                    wx1, wh1, wx2, wh2,
                                    xh, W0T, W1T, W2T, bcomb, H0a, H1b, H2a);

  // 22 anti-diagonal wavefronts: z0(t=wv), z1(t=wv-1), z2(t=wv-2)
  for (int wv = 0; wv < 22; ++wv) {
    const int cur = wv & 1;
    f16* H0c = cur ? H0b : H0a;  f16* H0n = cur ? H0a : H0b;
    f16* H1c = cur ? H1b : H1a;  f16* H1n = cur ? H1a : H1b;
    f16* H2c = cur ? H2b : H2a;  f16* H2n = cur ? H2a : H2b;
    rnn_step<<<512, 256, 0, stream>>>(wv, xh, W0T, W1T, W2T, bcomb, b1, b2,
                                      H0c, H0n, H1c, H1n, H2c, H2n);
  }

  // h2(19) written at wv=21 into H2n(cur=1) = H2a
  fc_kernel<<<160, 256, 0, stream>>>(H2a, W_fc, b_fc, out);
}